// Round 2
// baseline (3828.461 us; speedup 1.0000x reference)
//
#include <hip/hip_runtime.h>
#include <hip/hip_bf16.h>

#define L_ 1024
#define B_ 4
#define D_ 1024
#define PROJ_ 256
#define H_ 8
#define V_ 32000
#define M_ (L_ * B_)   // 4096 GEMM rows

typedef __bf16 bf16x8 __attribute__((ext_vector_type(8)));
typedef float f32x4 __attribute__((ext_vector_type(4)));

// ---------------- embedding gather -> bf16 ----------------
__global__ __launch_bounds__(256) void k_embed(const int* __restrict__ x,
                                               const float* __restrict__ emb,
                                               __hip_bfloat16* __restrict__ h) {
  int gid = blockIdx.x * 256 + threadIdx.x;   // one thread per 4 elements
  int row = gid >> 8;                          // 256 groups of 4 per row of 1024
  int d0 = (gid & 255) << 2;
  int tok = x[row];
  const float4 v = *(const float4*)(emb + (size_t)tok * D_ + d0);
  union { __hip_bfloat16 o[4]; uint2 u; } cv;
  cv.o[0] = __float2bfloat16(v.x);
  cv.o[1] = __float2bfloat16(v.y);
  cv.o[2] = __float2bfloat16(v.z);
  cv.o[3] = __float2bfloat16(v.w);
  *(uint2*)(h + (size_t)row * D_ + d0) = cv.u;
}

// ---------------- 128x128x32 bf16 MFMA GEMM, B is fp32 (converted in staging) ----
// CLS=false: C = A*B written as bf16 (row-major, stride N)
// CLS=true : classifier epilogue: adds bout, per-row 64-col-chunk (max,sumexp)
//            partials -> lse[chunk*4096+row], y-logit extraction -> logitY[row]
template <bool CLS>
__global__ __launch_bounds__(256) void k_gemm(
    const __hip_bfloat16* __restrict__ A, const float* __restrict__ B,
    __hip_bfloat16* __restrict__ C, int K, int N,
    const float* __restrict__ bout, const int* __restrict__ y,
    float2* __restrict__ lse, float* __restrict__ logitY) {
  __shared__ __hip_bfloat16 As[128 * 40];  // [m][k], stride 40 (pad 8) bf16
  __shared__ __hip_bfloat16 Bs[128 * 40];  // [n][k] transposed, stride 40
  const int tid = threadIdx.x;
  const int lane = tid & 63, wave = tid >> 6;
  const int quad = lane >> 4, l16 = lane & 15;
  const int wm = wave & 1, wn = wave >> 1;   // wave grid 2x2 over (M,N)
  const int row0 = blockIdx.x * 128, col0 = blockIdx.y * 128;

  f32x4 acc[4][4] = {};

  const int a_m = tid >> 1, a_k = (tid & 1) << 4;   // 16 bf16 per thread
  const int b_k = tid >> 3, b_n = (tid & 7) << 4;   // 16 fp32 per thread

  for (int k0 = 0; k0 < K; k0 += 32) {
    const uint4* ap = (const uint4*)(A + (size_t)(row0 + a_m) * K + k0 + a_k);
    uint4 av0 = ap[0];
    uint4 av1 = ap[1];
    const float* bp = B + (size_t)(k0 + b_k) * N + col0 + b_n;
    float4 bv0 = *(const float4*)(bp + 0);
    float4 bv1 = *(const float4*)(bp + 4);
    float4 bv2 = *(const float4*)(bp + 8);
    float4 bv3 = *(const float4*)(bp + 12);
    __syncthreads();  // protect LDS from previous iteration's readers
    *(uint4*)(As + a_m * 40 + a_k) = av0;
    *(uint4*)(As + a_m * 40 + a_k + 8) = av1;
    {
      float tmp[16] = {bv0.x, bv0.y, bv0.z, bv0.w, bv1.x, bv1.y, bv1.z, bv1.w,
                       bv2.x, bv2.y, bv2.z, bv2.w, bv3.x, bv3.y, bv3.z, bv3.w};
#pragma unroll
      for (int j = 0; j < 16; j++)
        Bs[(b_n + j) * 40 + b_k] = __float2bfloat16(tmp[j]);
    }
    __syncthreads();
    bf16x8 af[4], bfr[4];
#pragma unroll
    for (int mi = 0; mi < 4; mi++)
      af[mi] = *(const bf16x8*)(As + (wm * 64 + mi * 16 + l16) * 40 + quad * 8);
#pragma unroll
    for (int ni = 0; ni < 4; ni++)
      bfr[ni] = *(const bf16x8*)(Bs + (wn * 64 + ni * 16 + l16) * 40 + quad * 8);
#pragma unroll
    for (int mi = 0; mi < 4; mi++)
#pragma unroll
      for (int ni = 0; ni < 4; ni++)
        acc[mi][ni] = __builtin_amdgcn_mfma_f32_16x16x32_bf16(af[mi], bfr[ni],
                                                              acc[mi][ni], 0, 0, 0);
  }

  if constexpr (!CLS) {
#pragma unroll
    for (int mi = 0; mi < 4; mi++)
#pragma unroll
      for (int ni = 0; ni < 4; ni++)
#pragma unroll
        for (int r = 0; r < 4; r++) {
          int row = row0 + wm * 64 + mi * 16 + quad * 4 + r;
          int col = col0 + wn * 64 + ni * 16 + l16;
          C[(size_t)row * N + col] = __float2bfloat16(acc[mi][ni][r]);
        }
  } else {
    const int chunk = blockIdx.y * 2 + wn;  // 64-col chunks, 500 total
    float bv[4];
#pragma unroll
    for (int ni = 0; ni < 4; ni++)
      bv[ni] = bout[col0 + wn * 64 + ni * 16 + l16];
#pragma unroll
    for (int mi = 0; mi < 4; mi++) {
#pragma unroll
      for (int r = 0; r < 4; r++) {
        int row = row0 + wm * 64 + mi * 16 + quad * 4 + r;
        float v0 = acc[mi][0][r] + bv[0];
        float v1 = acc[mi][1][r] + bv[1];
        float v2 = acc[mi][2][r] + bv[2];
        float v3 = acc[mi][3][r] + bv[3];
        int yv = y[row];
        int cb = col0 + wn * 64 + l16;
        if (yv == cb + 0)  logitY[row] = v0;
        if (yv == cb + 16) logitY[row] = v1;
        if (yv == cb + 32) logitY[row] = v2;
        if (yv == cb + 48) logitY[row] = v3;
        float m = fmaxf(fmaxf(v0, v1), fmaxf(v2, v3));
#pragma unroll
        for (int off = 1; off < 16; off <<= 1)
          m = fmaxf(m, __shfl_xor(m, off, 64));
        float s = __expf(v0 - m) + __expf(v1 - m) + __expf(v2 - m) + __expf(v3 - m);
#pragma unroll
        for (int off = 1; off < 16; off <<= 1)
          s += __shfl_xor(s, off, 64);
        if (l16 == 0)
          lse[(size_t)chunk * M_ + row] = make_float2(m, s);
      }
    }
  }
}

// ---------------- attention (scores -> softmax -> PV), 8-row Q tiles ----------
__global__ __launch_bounds__(256) void k_attn(const __hip_bfloat16* __restrict__ z,
                                              const __hip_bfloat16* __restrict__ kv,
                                              __hip_bfloat16* __restrict__ ao,
                                              const float* __restrict__ alpha_p) {
  __shared__ float S[8 * 1024];      // scores / probs
  __shared__ float kvt[128 * 33];    // k or v tile, padded
  __shared__ float qs[8 * 32];
  __shared__ float red[8 * 32];
  __shared__ float rowmax[8];
  __shared__ float rowsum[8];
  const int tid = threadIdx.x;
  const int l0 = blockIdx.x * 8;
  const int pair = blockIdx.y;
  const int b = pair >> 3, h = pair & 7;
  const float scale = 0.17677669529663687f;  // 32^-0.5
  const float alpha = alpha_p[0];

  for (int i = tid; i < 8 * 32; i += 256) {
    int r = i >> 5, d = i & 31;
    qs[i] = __bfloat162float(z[((size_t)(l0 + r) * B_ + b) * PROJ_ + h * 32 + d]) * scale;
  }
  const int smax = l0 + 7;
  const int ntile = (smax + 128) / 128;  // ceil((smax+1)/128)

  // phase 1: scores (masked entries = -1e30)
  for (int t = 0; t < ntile; t++) {
    int s0 = t * 128;
    __syncthreads();
    for (int i = tid; i < 128 * 32; i += 256) {
      int j = i >> 5, d = i & 31;
      int s = s0 + j;
      kvt[j * 33 + d] = (s <= smax)
          ? __bfloat162float(kv[((size_t)s * B_ + b) * 512 + h * 32 + d]) : 0.f;
    }
    __syncthreads();
    for (int i = tid; i < 8 * 128; i += 256) {
      int r = i >> 7, j = i & 127;
      int s = s0 + j;
      float a = -1e30f;
      if (s <= l0 + r) {
        a = 0.f;
#pragma unroll
        for (int d = 0; d < 32; d++) a += qs[r * 32 + d] * kvt[j * 33 + d];
      }
      S[r * 1024 + s] = a;
    }
  }
  __syncthreads();
  const int ns = ntile * 128;
  // softmax stats (32 threads per row)
  {
    int r = tid >> 5, c = tid & 31;
    float m = -1e30f;
    for (int s = c; s < ns; s += 32) m = fmaxf(m, S[r * 1024 + s]);
    red[r * 32 + c] = m;
  }
  __syncthreads();
  if (tid < 8) {
    float m = -1e30f;
    for (int c = 0; c < 32; c++) m = fmaxf(m, red[tid * 32 + c]);
    rowmax[tid] = m;
  }
  __syncthreads();
  {
    int r = tid >> 5, c = tid & 31;
    float m = rowmax[r], sm = 0.f;
    for (int s = c; s < ns; s += 32) {
      float e = __expf(S[r * 1024 + s] - m);
      S[r * 1024 + s] = e;
      sm += e;
    }
    red[r * 32 + c] = sm;
  }
  __syncthreads();
  if (tid < 8) {
    float sm = 0.f;
    for (int c = 0; c < 32; c++) sm += red[tid * 32 + c];
    rowsum[tid] = sm;
  }
  // phase 2: PV (one output element per thread)
  const int r0 = tid >> 5, d0 = tid & 31;
  float o = 0.f;
  for (int t = 0; t < ntile; t++) {
    int s0 = t * 128;
    __syncthreads();
    for (int i = tid; i < 128 * 32; i += 256) {
      int j = i >> 5, d = i & 31;
      int s = s0 + j;
      kvt[j * 33 + d] = (s <= smax)
          ? __bfloat162float(kv[((size_t)s * B_ + b) * 512 + 256 + h * 32 + d]) : 0.f;
    }
    __syncthreads();
#pragma unroll 4
    for (int j = 0; j < 128; j++)
      o += S[r0 * 1024 + s0 + j] * kvt[j * 33 + d0];
  }
  size_t oi = ((size_t)(l0 + r0) * B_ + b) * PROJ_ + h * 32 + d0;
  float res = __bfloat162float(z[oi]);
  ao[oi] = __float2bfloat16(o / rowsum[r0] * alpha + res);
}

// ---------------- SRU recurrence: one thread per (b,d) channel ----------------
__global__ __launch_bounds__(256) void k_sru(const __hip_bfloat16* __restrict__ U,
                                             __hip_bfloat16* __restrict__ h,
                                             const float* __restrict__ hidden,
                                             const float* __restrict__ wc,
                                             const float* __restrict__ bias) {
  int tid = blockIdx.x * 256 + threadIdx.x;  // 0..4095
  int b = tid >> 10, d = tid & 1023;
  float vf = wc[d], vr = wc[D_ + d];
  float bf = bias[d], br = bias[D_ + d];
  float c = hidden[b * D_ + d];
  size_t ui = (size_t)b * 3 * D_ + 3 * d;
  size_t hi = (size_t)b * D_ + d;
  for (int l = 0; l < L_; l++) {
    float u0 = __bfloat162float(U[ui]);
    float u1 = __bfloat162float(U[ui + 1]) + bf;
    float u2 = __bfloat162float(U[ui + 2]) + br;
    float res = __bfloat162float(h[hi]);
    float f = 1.f / (1.f + __expf(-(u1 + vf * c)));
    c = f * c + (1.f - f) * u0;
    float r = 1.f / (1.f + __expf(-(u2 + vr * c)));
    h[hi] = __float2bfloat16(r * c + (1.f - r) * res);
    ui += (size_t)B_ * 3 * D_;
    hi += (size_t)B_ * D_;
  }
}

// ---------------- finalize: combine chunk partials -> loss (fp32 output!) -----
__global__ __launch_bounds__(256) void k_finalize(const float2* __restrict__ lse,
                                                  const float* __restrict__ logitY,
                                                  float* __restrict__ out) {
  int row = blockIdx.x * 256 + threadIdx.x;
  float M = -1e30f, S = 0.f;
  for (int c = 0; c < V_ / 64; c++) {
    float2 p = lse[(size_t)c * M_ + row];
    if (p.x > M) {
      S = S * __expf(M - p.x) + p.y;
      M = p.x;
    } else {
      S += p.y * __expf(p.x - M);
    }
  }
  out[row] = M + logf(S) - logitY[row];
}

extern "C" void kernel_launch(void* const* d_in, const int* in_sizes, int n_in,
                              void* d_out, int out_size, void* d_ws, size_t ws_size,
                              hipStream_t stream) {
  const int* x = (const int*)d_in[0];
  const int* y = (const int*)d_in[1];
  const float* hidden = (const float*)d_in[2];
  const float* emb = (const float*)d_in[3];
  const float* W1 = (const float*)d_in[4];
  const float* W2 = (const float*)d_in[5];
  const float* W3 = (const float*)d_in[6];
  const float* alpha = (const float*)d_in[7];
  const float* wc = (const float*)d_in[8];
  const float* bias = (const float*)d_in[9];
  const float* Wout = (const float*)d_in[10];
  const float* bout = (const float*)d_in[11];

  char* ws = (char*)d_ws;
  __hip_bfloat16* h16  = (__hip_bfloat16*)(ws + 0);         // 8 MB
  __hip_bfloat16* z16  = (__hip_bfloat16*)(ws + 8388608);   // 2 MB
  __hip_bfloat16* kv16 = (__hip_bfloat16*)(ws + 10485760);  // 4 MB
  __hip_bfloat16* ao16 = (__hip_bfloat16*)(ws + 14680064);  // 2 MB
  __hip_bfloat16* U16  = (__hip_bfloat16*)(ws + 16777216);  // 24 MB
  float2* lse          = (float2*)(ws + 41943040);          // 16 MB (500*4096*8)
  float* logitY        = (float*)(ws + 58327040);           // 16 KB
  float* out           = (float*)d_out;                     // fp32 loss (L,B)

  k_embed<<<4096, 256, 0, stream>>>(x, emb, h16);
  for (int i = 0; i < 4; i++) {
    k_gemm<false><<<dim3(32, 2), 256, 0, stream>>>(
        h16, W1 + (size_t)i * D_ * PROJ_, z16, D_, PROJ_,
        nullptr, nullptr, nullptr, nullptr);
    k_gemm<false><<<dim3(32, 4), 256, 0, stream>>>(
        z16, W2 + (size_t)i * PROJ_ * 2 * PROJ_, kv16, PROJ_, 2 * PROJ_,
        nullptr, nullptr, nullptr, nullptr);
    k_attn<<<dim3(L_ / 8, B_ * H_), 256, 0, stream>>>(z16, kv16, ao16, alpha + i);
    k_gemm<false><<<dim3(32, 24), 256, 0, stream>>>(
        ao16, W3 + (size_t)i * PROJ_ * 3 * D_, U16, PROJ_, 3 * D_,
        nullptr, nullptr, nullptr, nullptr);
    k_sru<<<16, 256, 0, stream>>>(U16, h16, hidden + (size_t)i * B_ * D_,
                                  wc + (size_t)i * 2 * D_, bias + (size_t)i * 2 * D_);
  }
  k_gemm<true><<<dim3(32, V_ / 128), 256, 0, stream>>>(
      h16, Wout, nullptr, D_, V_, bout, y, lse, logitY);
  k_finalize<<<16, 256, 0, stream>>>(lse, logitY, out);
}

// Round 3
// 2850.044 us; speedup vs baseline: 1.3433x; 1.3433x over previous
//
#include <hip/hip_runtime.h>
#include <hip/hip_bf16.h>
#include <stdint.h>

#define L_ 1024
#define B_ 4
#define D_ 1024
#define PROJ_ 256
#define H_ 8
#define V_ 32000
#define M_ 4096

typedef __bf16 bf16x8 __attribute__((ext_vector_type(8)));
typedef float f32x4 __attribute__((ext_vector_type(4)));

#define AS3(p) ((__attribute__((address_space(3))) void*)(p))
#define AS1(p) ((const __attribute__((address_space(1))) void*)(p))

// ---------------- embedding gather -> bf16 ----------------
__global__ __launch_bounds__(256) void k_embed(const int* __restrict__ x,
                                               const float* __restrict__ emb,
                                               __hip_bfloat16* __restrict__ h) {
  int gid = blockIdx.x * 256 + threadIdx.x;
  int row = gid >> 8;
  int d0 = (gid & 255) << 2;
  int tok = x[row];
  const float4 v = *(const float4*)(emb + (size_t)tok * D_ + d0);
  union { __hip_bfloat16 o[4]; uint2 u; } cv;
  cv.o[0] = __float2bfloat16(v.x);
  cv.o[1] = __float2bfloat16(v.y);
  cv.o[2] = __float2bfloat16(v.z);
  cv.o[3] = __float2bfloat16(v.w);
  *(uint2*)(h + (size_t)row * D_ + d0) = cv.u;
}

// ------------- transpose-convert: fp32 [K][N] -> bf16 [N][K], layer batched ---
__global__ __launch_bounds__(256) void k_transpose(const float* __restrict__ in,
                                                   __hip_bfloat16* __restrict__ out,
                                                   int K, int N,
                                                   long in_stride, long out_stride) {
  __shared__ float t[64][65];
  in += (size_t)blockIdx.z * in_stride;
  out += (size_t)blockIdx.z * out_stride;
  int n0 = blockIdx.x * 64, k0 = blockIdx.y * 64;
  int r = threadIdx.x >> 4, c4 = (threadIdx.x & 15) << 2;
#pragma unroll
  for (int p = 0; p < 4; p++) {
    float4 v = *(const float4*)(in + (size_t)(k0 + p * 16 + r) * N + n0 + c4);
    t[p * 16 + r][c4 + 0] = v.x;
    t[p * 16 + r][c4 + 1] = v.y;
    t[p * 16 + r][c4 + 2] = v.z;
    t[p * 16 + r][c4 + 3] = v.w;
  }
  __syncthreads();
  int n = threadIdx.x >> 2, kg = (threadIdx.x & 3) << 4;
  union { __hip_bfloat16 b[16]; uint4 u[2]; } cv;
#pragma unroll
  for (int i = 0; i < 16; i++) cv.b[i] = __float2bfloat16(t[kg + i][n]);
  uint4* op = (uint4*)(out + (size_t)(n0 + n) * K + k0 + kg);
  op[0] = cv.u[0];
  op[1] = cv.u[1];
}

// ------------- m97-style GEMM: A[M][K] bf16, Bt[N][K] bf16, 128x128 tile, BK=64 ---
// CLS epilogue: per-row 64-col-chunk (max,sumexp) partials + y-logit extraction.
template <bool CLS>
__global__ __launch_bounds__(256) void k_gemm_bt(
    const __hip_bfloat16* __restrict__ A, const __hip_bfloat16* __restrict__ Bt,
    __hip_bfloat16* __restrict__ C, int K, int N,
    const float* __restrict__ bout, const int* __restrict__ y,
    float2* __restrict__ lse, float* __restrict__ logitY) {
  __shared__ __hip_bfloat16 As[128 * 64];
  __shared__ __hip_bfloat16 Bs[128 * 64];
  const int tid = threadIdx.x;
  const int lane = tid & 63, wave = tid >> 6;
  const int quad = lane >> 4, l16 = lane & 15;
  const int wm = wave & 1, wn = wave >> 1;
  const int row0 = blockIdx.x * 128, col0 = blockIdx.y * 128;

  f32x4 acc[4][4] = {};

  const __hip_bfloat16* Abase = A + (size_t)row0 * K;
  const __hip_bfloat16* Bbase = Bt + (size_t)col0 * K;
  const int m_s = tid >> 3;              // chunk row for call 0
  const int ko_s = (tid & 7) << 3;       // chunk k-offset (elems)

  for (int k0 = 0; k0 < K; k0 += 64) {
    __syncthreads();
#pragma unroll
    for (int call = 0; call < 4; call++) {
      int m = m_s + call * 32;           // c = call*256+tid ; m = c>>3
      __builtin_amdgcn_global_load_lds(AS1(Abase + (size_t)m * K + k0 + ko_s),
                                       AS3(As + (call * 256 + wave * 64) * 8),
                                       16, 0, 0);
      __builtin_amdgcn_global_load_lds(AS1(Bbase + (size_t)m * K + k0 + ko_s),
                                       AS3(Bs + (call * 256 + wave * 64) * 8),
                                       16, 0, 0);
    }
    __syncthreads();
#pragma unroll
    for (int kk = 0; kk < 2; kk++) {
      bf16x8 af[4], bfr[4];
#pragma unroll
      for (int mi = 0; mi < 4; mi++)
        af[mi] = *(const bf16x8*)(As + (wm * 64 + mi * 16 + l16) * 64 + kk * 32 + quad * 8);
#pragma unroll
      for (int ni = 0; ni < 4; ni++)
        bfr[ni] = *(const bf16x8*)(Bs + (wn * 64 + ni * 16 + l16) * 64 + kk * 32 + quad * 8);
#pragma unroll
      for (int mi = 0; mi < 4; mi++)
#pragma unroll
        for (int ni = 0; ni < 4; ni++)
          acc[mi][ni] = __builtin_amdgcn_mfma_f32_16x16x32_bf16(af[mi], bfr[ni],
                                                                acc[mi][ni], 0, 0, 0);
    }
  }

  if constexpr (!CLS) {
#pragma unroll
    for (int mi = 0; mi < 4; mi++)
#pragma unroll
      for (int ni = 0; ni < 4; ni++)
#pragma unroll
        for (int r = 0; r < 4; r++) {
          int row = row0 + wm * 64 + mi * 16 + quad * 4 + r;
          int col = col0 + wn * 64 + ni * 16 + l16;
          C[(size_t)row * N + col] = __float2bfloat16(acc[mi][ni][r]);
        }
  } else {
    const int chunk = blockIdx.y * 2 + wn;
    float bv[4];
#pragma unroll
    for (int ni = 0; ni < 4; ni++)
      bv[ni] = bout[col0 + wn * 64 + ni * 16 + l16];
#pragma unroll
    for (int mi = 0; mi < 4; mi++) {
#pragma unroll
      for (int r = 0; r < 4; r++) {
        int row = row0 + wm * 64 + mi * 16 + quad * 4 + r;
        float v0 = acc[mi][0][r] + bv[0];
        float v1 = acc[mi][1][r] + bv[1];
        float v2 = acc[mi][2][r] + bv[2];
        float v3 = acc[mi][3][r] + bv[3];
        int yv = y[row];
        int cb = col0 + wn * 64 + l16;
        if (yv == cb + 0)  logitY[row] = v0;
        if (yv == cb + 16) logitY[row] = v1;
        if (yv == cb + 32) logitY[row] = v2;
        if (yv == cb + 48) logitY[row] = v3;
        float m = fmaxf(fmaxf(v0, v1), fmaxf(v2, v3));
#pragma unroll
        for (int off = 1; off < 16; off <<= 1)
          m = fmaxf(m, __shfl_xor(m, off, 64));
        float s = __expf(v0 - m) + __expf(v1 - m) + __expf(v2 - m) + __expf(v3 - m);
#pragma unroll
        for (int off = 1; off < 16; off <<= 1)
          s += __shfl_xor(s, off, 64);
        if (l16 == 0)
          lse[(size_t)chunk * M_ + row] = make_float2(m, s);
      }
    }
  }
}

// ------------- fallback classifier: fp32 B staged through LDS (validated R1) ---
__global__ __launch_bounds__(256) void k_gemm_cls_f32(
    const __hip_bfloat16* __restrict__ A, const float* __restrict__ B,
    int K, int N, const float* __restrict__ bout, const int* __restrict__ y,
    float2* __restrict__ lse, float* __restrict__ logitY) {
  __shared__ __hip_bfloat16 As[128 * 40];
  __shared__ __hip_bfloat16 Bs[128 * 40];
  const int tid = threadIdx.x;
  const int lane = tid & 63, wave = tid >> 6;
  const int quad = lane >> 4, l16 = lane & 15;
  const int wm = wave & 1, wn = wave >> 1;
  const int row0 = blockIdx.x * 128, col0 = blockIdx.y * 128;
  f32x4 acc[4][4] = {};
  const int a_m = tid >> 1, a_k = (tid & 1) << 4;
  const int b_k = tid >> 3, b_n = (tid & 7) << 4;
  for (int k0 = 0; k0 < K; k0 += 32) {
    const uint4* ap = (const uint4*)(A + (size_t)(row0 + a_m) * K + k0 + a_k);
    uint4 av0 = ap[0];
    uint4 av1 = ap[1];
    const float* bp = B + (size_t)(k0 + b_k) * N + col0 + b_n;
    float4 bv0 = *(const float4*)(bp + 0);
    float4 bv1 = *(const float4*)(bp + 4);
    float4 bv2 = *(const float4*)(bp + 8);
    float4 bv3 = *(const float4*)(bp + 12);
    __syncthreads();
    *(uint4*)(As + a_m * 40 + a_k) = av0;
    *(uint4*)(As + a_m * 40 + a_k + 8) = av1;
    {
      float tmp[16] = {bv0.x, bv0.y, bv0.z, bv0.w, bv1.x, bv1.y, bv1.z, bv1.w,
                       bv2.x, bv2.y, bv2.z, bv2.w, bv3.x, bv3.y, bv3.z, bv3.w};
#pragma unroll
      for (int j = 0; j < 16; j++)
        Bs[(b_n + j) * 40 + b_k] = __float2bfloat16(tmp[j]);
    }
    __syncthreads();
    bf16x8 af[4], bfr[4];
#pragma unroll
    for (int mi = 0; mi < 4; mi++)
      af[mi] = *(const bf16x8*)(As + (wm * 64 + mi * 16 + l16) * 40 + quad * 8);
#pragma unroll
    for (int ni = 0; ni < 4; ni++)
      bfr[ni] = *(const bf16x8*)(Bs + (wn * 64 + ni * 16 + l16) * 40 + quad * 8);
#pragma unroll
    for (int mi = 0; mi < 4; mi++)
#pragma unroll
      for (int ni = 0; ni < 4; ni++)
        acc[mi][ni] = __builtin_amdgcn_mfma_f32_16x16x32_bf16(af[mi], bfr[ni],
                                                              acc[mi][ni], 0, 0, 0);
  }
  const int chunk = blockIdx.y * 2 + wn;
  float bv[4];
#pragma unroll
  for (int ni = 0; ni < 4; ni++)
    bv[ni] = bout[col0 + wn * 64 + ni * 16 + l16];
#pragma unroll
  for (int mi = 0; mi < 4; mi++) {
#pragma unroll
    for (int r = 0; r < 4; r++) {
      int row = row0 + wm * 64 + mi * 16 + quad * 4 + r;
      float v0 = acc[mi][0][r] + bv[0];
      float v1 = acc[mi][1][r] + bv[1];
      float v2 = acc[mi][2][r] + bv[2];
      float v3 = acc[mi][3][r] + bv[3];
      int yv = y[row];
      int cb = col0 + wn * 64 + l16;
      if (yv == cb + 0)  logitY[row] = v0;
      if (yv == cb + 16) logitY[row] = v1;
      if (yv == cb + 32) logitY[row] = v2;
      if (yv == cb + 48) logitY[row] = v3;
      float m = fmaxf(fmaxf(v0, v1), fmaxf(v2, v3));
#pragma unroll
      for (int off = 1; off < 16; off <<= 1)
        m = fmaxf(m, __shfl_xor(m, off, 64));
      float s = __expf(v0 - m) + __expf(v1 - m) + __expf(v2 - m) + __expf(v3 - m);
#pragma unroll
      for (int off = 1; off < 16; off <<= 1)
        s += __shfl_xor(s, off, 64);
      if (l16 == 0)
        lse[(size_t)chunk * M_ + row] = make_float2(m, s);
    }
  }
}

// ---------------- attention (unchanged from validated R1) ----------------
__global__ __launch_bounds__(256) void k_attn(const __hip_bfloat16* __restrict__ z,
                                              const __hip_bfloat16* __restrict__ kv,
                                              __hip_bfloat16* __restrict__ ao,
                                              const float* __restrict__ alpha_p) {
  __shared__ float S[8 * 1024];
  __shared__ float kvt[128 * 33];
  __shared__ float qs[8 * 32];
  __shared__ float red[8 * 32];
  __shared__ float rowmax[8];
  __shared__ float rowsum[8];
  const int tid = threadIdx.x;
  const int l0 = blockIdx.x * 8;
  const int pair = blockIdx.y;
  const int b = pair >> 3, h = pair & 7;
  const float scale = 0.17677669529663687f;
  const float alpha = alpha_p[0];

  for (int i = tid; i < 8 * 32; i += 256) {
    int r = i >> 5, d = i & 31;
    qs[i] = __bfloat162float(z[((size_t)(l0 + r) * B_ + b) * PROJ_ + h * 32 + d]) * scale;
  }
  const int smax = l0 + 7;
  const int ntile = (smax + 128) / 128;

  for (int t = 0; t < ntile; t++) {
    int s0 = t * 128;
    __syncthreads();
    for (int i = tid; i < 128 * 32; i += 256) {
      int j = i >> 5, d = i & 31;
      int s = s0 + j;
      kvt[j * 33 + d] = (s <= smax)
          ? __bfloat162float(kv[((size_t)s * B_ + b) * 512 + h * 32 + d]) : 0.f;
    }
    __syncthreads();
    for (int i = tid; i < 8 * 128; i += 256) {
      int r = i >> 7, j = i & 127;
      int s = s0 + j;
      float a = -1e30f;
      if (s <= l0 + r) {
        a = 0.f;
#pragma unroll
        for (int d = 0; d < 32; d++) a += qs[r * 32 + d] * kvt[j * 33 + d];
      }
      S[r * 1024 + s] = a;
    }
  }
  __syncthreads();
  const int ns = ntile * 128;
  {
    int r = tid >> 5, c = tid & 31;
    float m = -1e30f;
    for (int s = c; s < ns; s += 32) m = fmaxf(m, S[r * 1024 + s]);
    red[r * 32 + c] = m;
  }
  __syncthreads();
  if (tid < 8) {
    float m = -1e30f;
    for (int c = 0; c < 32; c++) m = fmaxf(m, red[tid * 32 + c]);
    rowmax[tid] = m;
  }
  __syncthreads();
  {
    int r = tid >> 5, c = tid & 31;
    float m = rowmax[r], sm = 0.f;
    for (int s = c; s < ns; s += 32) {
      float e = __expf(S[r * 1024 + s] - m);
      S[r * 1024 + s] = e;
      sm += e;
    }
    red[r * 32 + c] = sm;
  }
  __syncthreads();
  if (tid < 8) {
    float sm = 0.f;
    for (int c = 0; c < 32; c++) sm += red[tid * 32 + c];
    rowsum[tid] = sm;
  }
  const int r0 = tid >> 5, d0 = tid & 31;
  float o = 0.f;
  for (int t = 0; t < ntile; t++) {
    int s0 = t * 128;
    __syncthreads();
    for (int i = tid; i < 128 * 32; i += 256) {
      int j = i >> 5, d = i & 31;
      int s = s0 + j;
      kvt[j * 33 + d] = (s <= smax)
          ? __bfloat162float(kv[((size_t)s * B_ + b) * 512 + 256 + h * 32 + d]) : 0.f;
    }
    __syncthreads();
#pragma unroll 4
    for (int j = 0; j < 128; j++)
      o += S[r0 * 1024 + s0 + j] * kvt[j * 33 + d0];
  }
  size_t oi = ((size_t)(l0 + r0) * B_ + b) * PROJ_ + h * 32 + d0;
  float res = __bfloat162float(z[oi]);
  ao[oi] = __float2bfloat16(o / rowsum[r0] * alpha + res);
}

// ------------- SRU: 64 blocks x 64 thr, 8-step register prefetch chunks -------
__global__ __launch_bounds__(64) void k_sru(const __hip_bfloat16* __restrict__ U,
                                            __hip_bfloat16* __restrict__ h,
                                            const float* __restrict__ hidden,
                                            const float* __restrict__ wc,
                                            const float* __restrict__ bias) {
  int tid = blockIdx.x * 64 + threadIdx.x;  // 0..4095
  int b = tid >> 10, d = tid & 1023;
  float vf = wc[d], vr = wc[D_ + d];
  float bfs = bias[d], brs = bias[D_ + d];
  float c = hidden[b * D_ + d];
  const __hip_bfloat16* up = U + (size_t)b * 3 * D_ + 3 * d;
  __hip_bfloat16* hp = h + (size_t)b * D_ + d;
  const int US = B_ * 3 * D_, HS = B_ * D_;
  for (int l0 = 0; l0 < L_; l0 += 8) {
    float u0[8], u1[8], u2[8], rs[8];
#pragma unroll
    for (int j = 0; j < 8; j++) {
      u0[j] = __bfloat162float(up[(size_t)j * US + 0]);
      u1[j] = __bfloat162float(up[(size_t)j * US + 1]);
      u2[j] = __bfloat162float(up[(size_t)j * US + 2]);
      rs[j] = __bfloat162float(hp[(size_t)j * HS]);
    }
#pragma unroll
    for (int j = 0; j < 8; j++) {
      float f = __builtin_amdgcn_rcpf(1.f + __expf(-(u1[j] + bfs + vf * c)));
      c = u0[j] + f * (c - u0[j]);
      float r = __builtin_amdgcn_rcpf(1.f + __expf(-(u2[j] + brs + vr * c)));
      hp[(size_t)j * HS] = __float2bfloat16(rs[j] + r * (c - rs[j]));
    }
    up += (size_t)8 * US;
    hp += (size_t)8 * HS;
  }
}

// ---------------- finalize: combine chunk partials -> fp32 loss ----------------
__global__ __launch_bounds__(256) void k_finalize(const float2* __restrict__ lse,
                                                  const float* __restrict__ logitY,
                                                  float* __restrict__ out) {
  int row = blockIdx.x * 256 + threadIdx.x;
  float M = -1e30f, S = 0.f;
  for (int c = 0; c < V_ / 64; c++) {
    float2 p = lse[(size_t)c * M_ + row];
    if (p.x > M) {
      S = S * __expf(M - p.x) + p.y;
      M = p.x;
    } else {
      S += p.y * __expf(p.x - M);
    }
  }
  out[row] = M + logf(S) - logitY[row];
}

extern "C" void kernel_launch(void* const* d_in, const int* in_sizes, int n_in,
                              void* d_out, int out_size, void* d_ws, size_t ws_size,
                              hipStream_t stream) {
  const int* x = (const int*)d_in[0];
  const int* y = (const int*)d_in[1];
  const float* hidden = (const float*)d_in[2];
  const float* emb = (const float*)d_in[3];
  const float* W1 = (const float*)d_in[4];
  const float* W2 = (const float*)d_in[5];
  const float* W3 = (const float*)d_in[6];
  const float* alpha = (const float*)d_in[7];
  const float* wc = (const float*)d_in[8];
  const float* bias = (const float*)d_in[9];
  const float* Wout = (const float*)d_in[10];
  const float* bout = (const float*)d_in[11];

  char* ws = (char*)d_ws;
  __hip_bfloat16* h16  = (__hip_bfloat16*)(ws + 0);          // 8 MB
  __hip_bfloat16* z16  = (__hip_bfloat16*)(ws + 8388608);    // 2 MB
  __hip_bfloat16* kv16 = (__hip_bfloat16*)(ws + 10485760);   // 4 MB
  __hip_bfloat16* ao16 = (__hip_bfloat16*)(ws + 14680064);   // 2 MB
  __hip_bfloat16* W1t  = (__hip_bfloat16*)(ws + 16777216);   // 2 MB  [4][256][1024]
  __hip_bfloat16* W2t  = (__hip_bfloat16*)(ws + 18874368);   // 1 MB  [4][512][256]
  __hip_bfloat16* W3t  = (__hip_bfloat16*)(ws + 19922944);   // 6 MB  [4][3072][256]
  __hip_bfloat16* U16  = (__hip_bfloat16*)(ws + 26214400);   // 24 MB
  const bool fast = ws_size >= 109723648ull;
  // fast: Woutt aliases U16 (written after last k_sru); lse separate.
  // fallback: lse aliases U16 (used only after last k_sru).
  __hip_bfloat16* Woutt = (__hip_bfloat16*)(ws + 26214400);  // 64 MB [32000][1024]
  float2* lse    = (float2*)(ws + (fast ? 93323264u : 26214400u));  // 16 MB
  float* logitY  = (float*)(ws + (fast ? 109707264u : 42598400u));  // 16 KB
  float* out     = (float*)d_out;

  k_embed<<<4096, 256, 0, stream>>>(x, emb, h16);
  k_transpose<<<dim3(4, 16, 4), 256, 0, stream>>>(W1, W1t, D_, PROJ_,
                                                  (long)D_ * PROJ_, (long)PROJ_ * D_);
  k_transpose<<<dim3(8, 4, 4), 256, 0, stream>>>(W2, W2t, PROJ_, 2 * PROJ_,
                                                 (long)PROJ_ * 2 * PROJ_,
                                                 (long)2 * PROJ_ * PROJ_);
  k_transpose<<<dim3(48, 4, 4), 256, 0, stream>>>(W3, W3t, PROJ_, 3 * D_,
                                                  (long)PROJ_ * 3 * D_,
                                                  (long)3 * D_ * PROJ_);
  for (int i = 0; i < 4; i++) {
    k_gemm_bt<false><<<dim3(32, 2), 256, 0, stream>>>(
        h16, W1t + (size_t)i * PROJ_ * D_, z16, D_, PROJ_,
        nullptr, nullptr, nullptr, nullptr);
    k_gemm_bt<false><<<dim3(32, 4), 256, 0, stream>>>(
        z16, W2t + (size_t)i * 2 * PROJ_ * PROJ_, kv16, PROJ_, 2 * PROJ_,
        nullptr, nullptr, nullptr, nullptr);
    k_attn<<<dim3(L_ / 8, B_ * H_), 256, 0, stream>>>(z16, kv16, ao16, alpha + i);
    k_gemm_bt<false><<<dim3(32, 24), 256, 0, stream>>>(
        ao16, W3t + (size_t)i * 3 * D_ * PROJ_, U16, PROJ_, 3 * D_,
        nullptr, nullptr, nullptr, nullptr);
    k_sru<<<64, 64, 0, stream>>>(U16, h16, hidden + (size_t)i * B_ * D_,
                                 wc + (size_t)i * 2 * D_, bias + (size_t)i * 2 * D_);
  }
  if (fast) {
    k_transpose<<<dim3(500, 16, 1), 256, 0, stream>>>(Wout, Woutt, D_, V_, 0, 0);
    k_gemm_bt<true><<<dim3(32, V_ / 128), 256, 0, stream>>>(
        h16, Woutt, nullptr, D_, V_, bout, y, lse, logitY);
  } else {
    k_gemm_cls_f32<<<dim3(32, V_ / 128), 256, 0, stream>>>(
        h16, Wout, D_, V_, bout, y, lse, logitY);
  }
  k_finalize<<<16, 256, 0, stream>>>(lse, logitY, out);
}

// Round 4
// 2671.385 us; speedup vs baseline: 1.4331x; 1.0669x over previous
//
#include <hip/hip_runtime.h>
#include <hip/hip_bf16.h>
#include <stdint.h>

#define L_ 1024
#define B_ 4
#define D_ 1024
#define PROJ_ 256
#define H_ 8
#define V_ 32000
#define M_ 4096

typedef __bf16 bf16x8 __attribute__((ext_vector_type(8)));
typedef float f32x4 __attribute__((ext_vector_type(4)));

#define AS3(p) ((__attribute__((address_space(3))) void*)(p))
#define AS1(p) ((const __attribute__((address_space(1))) void*)(p))

// ---------------- embedding gather -> bf16 ----------------
__global__ __launch_bounds__(256) void k_embed(const int* __restrict__ x,
                                               const float* __restrict__ emb,
                                               __hip_bfloat16* __restrict__ h) {
  int gid = blockIdx.x * 256 + threadIdx.x;
  int row = gid >> 8;
  int d0 = (gid & 255) << 2;
  int tok = x[row];
  const float4 v = *(const float4*)(emb + (size_t)tok * D_ + d0);
  union { __hip_bfloat16 o[4]; uint2 u; } cv;
  cv.o[0] = __float2bfloat16(v.x);
  cv.o[1] = __float2bfloat16(v.y);
  cv.o[2] = __float2bfloat16(v.z);
  cv.o[3] = __float2bfloat16(v.w);
  *(uint2*)(h + (size_t)row * D_ + d0) = cv.u;
}

// ------------- transpose-convert: fp32 [K][N] -> bf16 [N][K], layer batched ---
__global__ __launch_bounds__(256) void k_transpose(const float* __restrict__ in,
                                                   __hip_bfloat16* __restrict__ out,
                                                   int K, int N,
                                                   long in_stride, long out_stride) {
  __shared__ float t[64][65];
  in += (size_t)blockIdx.z * in_stride;
  out += (size_t)blockIdx.z * out_stride;
  int n0 = blockIdx.x * 64, k0 = blockIdx.y * 64;
  int r = threadIdx.x >> 4, c4 = (threadIdx.x & 15) << 2;
#pragma unroll
  for (int p = 0; p < 4; p++) {
    float4 v = *(const float4*)(in + (size_t)(k0 + p * 16 + r) * N + n0 + c4);
    t[p * 16 + r][c4 + 0] = v.x;
    t[p * 16 + r][c4 + 1] = v.y;
    t[p * 16 + r][c4 + 2] = v.z;
    t[p * 16 + r][c4 + 3] = v.w;
  }
  __syncthreads();
  int n = threadIdx.x >> 2, kg = (threadIdx.x & 3) << 4;
  union { __hip_bfloat16 b[16]; uint4 u[2]; } cv;
#pragma unroll
  for (int i = 0; i < 16; i++) cv.b[i] = __float2bfloat16(t[kg + i][n]);
  uint4* op = (uint4*)(out + (size_t)(n0 + n) * K + k0 + kg);
  op[0] = cv.u[0];
  op[1] = cv.u[1];
}

// ------------- m97-style GEMM + XOR-swizzled LDS: A[M][K] bf16, Bt[N][K] bf16 ---
// LDS slot (m, c) holds global chunk (m, c ^ (m&7)); reader XORs back. This makes
// the 16-lane ds_read_b128 column walk hit all 32 banks (2-way = free) instead of
// one 4-bank group (16-way). Data in fragments is bit-identical to the unswizzled
// version.
template <bool CLS>
__global__ __launch_bounds__(256) void k_gemm_bt(
    const __hip_bfloat16* __restrict__ A, const __hip_bfloat16* __restrict__ Bt,
    __hip_bfloat16* __restrict__ C, int K, int N,
    const float* __restrict__ bout, const int* __restrict__ y,
    float2* __restrict__ lse, float* __restrict__ logitY) {
  __shared__ __hip_bfloat16 As[128 * 64];
  __shared__ __hip_bfloat16 Bs[128 * 64];
  const int tid = threadIdx.x;
  const int lane = tid & 63, wave = tid >> 6;
  const int quad = lane >> 4, l16 = lane & 15;
  const int wm = wave & 1, wn = wave >> 1;
  const int row0 = blockIdx.x * 128, col0 = blockIdx.y * 128;

  f32x4 acc[4][4] = {};

  const __hip_bfloat16* Abase = A + (size_t)row0 * K;
  const __hip_bfloat16* Bbase = Bt + (size_t)col0 * K;
  const int m_s = tid >> 3;                         // slot row (call 0)
  const int ko_sw = (((tid & 7) ^ (m_s & 7)) << 3); // swizzled source k-off (elems)
  const int xr = l16 & 7;                           // reader xor key

  for (int k0 = 0; k0 < K; k0 += 64) {
    __syncthreads();
#pragma unroll
    for (int call = 0; call < 4; call++) {
      int m = m_s + call * 32;  // (call*32 ≡ 0 mod 8 → xor key unchanged)
      __builtin_amdgcn_global_load_lds(AS1(Abase + (size_t)m * K + k0 + ko_sw),
                                       AS3(As + (call * 256 + wave * 64) * 8),
                                       16, 0, 0);
      __builtin_amdgcn_global_load_lds(AS1(Bbase + (size_t)m * K + k0 + ko_sw),
                                       AS3(Bs + (call * 256 + wave * 64) * 8),
                                       16, 0, 0);
    }
    __syncthreads();
#pragma unroll
    for (int kk = 0; kk < 2; kk++) {
      bf16x8 af[4], bfr[4];
#pragma unroll
      for (int mi = 0; mi < 4; mi++)
        af[mi] = *(const bf16x8*)(As + (wm * 64 + mi * 16 + l16) * 64 +
                                  (((kk * 4 + quad) ^ xr) << 3));
#pragma unroll
      for (int ni = 0; ni < 4; ni++)
        bfr[ni] = *(const bf16x8*)(Bs + (wn * 64 + ni * 16 + l16) * 64 +
                                   (((kk * 4 + quad) ^ xr) << 3));
#pragma unroll
      for (int mi = 0; mi < 4; mi++)
#pragma unroll
        for (int ni = 0; ni < 4; ni++)
          acc[mi][ni] = __builtin_amdgcn_mfma_f32_16x16x32_bf16(af[mi], bfr[ni],
                                                                acc[mi][ni], 0, 0, 0);
    }
  }

  if constexpr (!CLS) {
#pragma unroll
    for (int mi = 0; mi < 4; mi++)
#pragma unroll
      for (int ni = 0; ni < 4; ni++)
#pragma unroll
        for (int r = 0; r < 4; r++) {
          int row = row0 + wm * 64 + mi * 16 + quad * 4 + r;
          int col = col0 + wn * 64 + ni * 16 + l16;
          C[(size_t)row * N + col] = __float2bfloat16(acc[mi][ni][r]);
        }
  } else {
    const int chunk = blockIdx.y * 2 + wn;
    float bv[4];
#pragma unroll
    for (int ni = 0; ni < 4; ni++)
      bv[ni] = bout[col0 + wn * 64 + ni * 16 + l16];
#pragma unroll
    for (int mi = 0; mi < 4; mi++) {
#pragma unroll
      for (int r = 0; r < 4; r++) {
        int row = row0 + wm * 64 + mi * 16 + quad * 4 + r;
        float v0 = acc[mi][0][r] + bv[0];
        float v1 = acc[mi][1][r] + bv[1];
        float v2 = acc[mi][2][r] + bv[2];
        float v3 = acc[mi][3][r] + bv[3];
        int yv = y[row];
        int cb = col0 + wn * 64 + l16;
        if (yv == cb + 0)  logitY[row] = v0;
        if (yv == cb + 16) logitY[row] = v1;
        if (yv == cb + 32) logitY[row] = v2;
        if (yv == cb + 48) logitY[row] = v3;
        float m = fmaxf(fmaxf(v0, v1), fmaxf(v2, v3));
#pragma unroll
        for (int off = 1; off < 16; off <<= 1)
          m = fmaxf(m, __shfl_xor(m, off, 64));
        float s = __expf(v0 - m) + __expf(v1 - m) + __expf(v2 - m) + __expf(v3 - m);
#pragma unroll
        for (int off = 1; off < 16; off <<= 1)
          s += __shfl_xor(s, off, 64);
        if (l16 == 0)
          lse[(size_t)chunk * M_ + row] = make_float2(m, s);
      }
    }
  }
}

// ------------- fallback classifier: fp32 B staged through LDS (validated R1) ---
__global__ __launch_bounds__(256) void k_gemm_cls_f32(
    const __hip_bfloat16* __restrict__ A, const float* __restrict__ B,
    int K, int N, const float* __restrict__ bout, const int* __restrict__ y,
    float2* __restrict__ lse, float* __restrict__ logitY) {
  __shared__ __hip_bfloat16 As[128 * 40];
  __shared__ __hip_bfloat16 Bs[128 * 40];
  const int tid = threadIdx.x;
  const int lane = tid & 63, wave = tid >> 6;
  const int quad = lane >> 4, l16 = lane & 15;
  const int wm = wave & 1, wn = wave >> 1;
  const int row0 = blockIdx.x * 128, col0 = blockIdx.y * 128;
  f32x4 acc[4][4] = {};
  const int a_m = tid >> 1, a_k = (tid & 1) << 4;
  const int b_k = tid >> 3, b_n = (tid & 7) << 4;
  for (int k0 = 0; k0 < K; k0 += 32) {
    const uint4* ap = (const uint4*)(A + (size_t)(row0 + a_m) * K + k0 + a_k);
    uint4 av0 = ap[0];
    uint4 av1 = ap[1];
    const float* bp = B + (size_t)(k0 + b_k) * N + col0 + b_n;
    float4 bv0 = *(const float4*)(bp + 0);
    float4 bv1 = *(const float4*)(bp + 4);
    float4 bv2 = *(const float4*)(bp + 8);
    float4 bv3 = *(const float4*)(bp + 12);
    __syncthreads();
    *(uint4*)(As + a_m * 40 + a_k) = av0;
    *(uint4*)(As + a_m * 40 + a_k + 8) = av1;
    {
      float tmp[16] = {bv0.x, bv0.y, bv0.z, bv0.w, bv1.x, bv1.y, bv1.z, bv1.w,
                       bv2.x, bv2.y, bv2.z, bv2.w, bv3.x, bv3.y, bv3.z, bv3.w};
#pragma unroll
      for (int j = 0; j < 16; j++)
        Bs[(b_n + j) * 40 + b_k] = __float2bfloat16(tmp[j]);
    }
    __syncthreads();
    bf16x8 af[4], bfr[4];
#pragma unroll
    for (int mi = 0; mi < 4; mi++)
      af[mi] = *(const bf16x8*)(As + (wm * 64 + mi * 16 + l16) * 40 + quad * 8);
#pragma unroll
    for (int ni = 0; ni < 4; ni++)
      bfr[ni] = *(const bf16x8*)(Bs + (wn * 64 + ni * 16 + l16) * 40 + quad * 8);
#pragma unroll
    for (int mi = 0; mi < 4; mi++)
#pragma unroll
      for (int ni = 0; ni < 4; ni++)
        acc[mi][ni] = __builtin_amdgcn_mfma_f32_16x16x32_bf16(af[mi], bfr[ni],
                                                              acc[mi][ni], 0, 0, 0);
  }
  const int chunk = blockIdx.y * 2 + wn;
  float bv[4];
#pragma unroll
  for (int ni = 0; ni < 4; ni++)
    bv[ni] = bout[col0 + wn * 64 + ni * 16 + l16];
#pragma unroll
  for (int mi = 0; mi < 4; mi++) {
#pragma unroll
    for (int r = 0; r < 4; r++) {
      int row = row0 + wm * 64 + mi * 16 + quad * 4 + r;
      float v0 = acc[mi][0][r] + bv[0];
      float v1 = acc[mi][1][r] + bv[1];
      float v2 = acc[mi][2][r] + bv[2];
      float v3 = acc[mi][3][r] + bv[3];
      int yv = y[row];
      int cb = col0 + wn * 64 + l16;
      if (yv == cb + 0)  logitY[row] = v0;
      if (yv == cb + 16) logitY[row] = v1;
      if (yv == cb + 32) logitY[row] = v2;
      if (yv == cb + 48) logitY[row] = v3;
      float m = fmaxf(fmaxf(v0, v1), fmaxf(v2, v3));
#pragma unroll
      for (int off = 1; off < 16; off <<= 1)
        m = fmaxf(m, __shfl_xor(m, off, 64));
      float s = __expf(v0 - m) + __expf(v1 - m) + __expf(v2 - m) + __expf(v3 - m);
#pragma unroll
      for (int off = 1; off < 16; off <<= 1)
        s += __shfl_xor(s, off, 64);
      if (l16 == 0)
        lse[(size_t)chunk * M_ + row] = make_float2(m, s);
    }
  }
}

// ---------------- attention (unchanged, validated) ----------------
__global__ __launch_bounds__(256) void k_attn(const __hip_bfloat16* __restrict__ z,
                                              const __hip_bfloat16* __restrict__ kv,
                                              __hip_bfloat16* __restrict__ ao,
                                              const float* __restrict__ alpha_p) {
  __shared__ float S[8 * 1024];
  __shared__ float kvt[128 * 33];
  __shared__ float qs[8 * 32];
  __shared__ float red[8 * 32];
  __shared__ float rowmax[8];
  __shared__ float rowsum[8];
  const int tid = threadIdx.x;
  const int l0 = blockIdx.x * 8;
  const int pair = blockIdx.y;
  const int b = pair >> 3, h = pair & 7;
  const float scale = 0.17677669529663687f;
  const float alpha = alpha_p[0];

  for (int i = tid; i < 8 * 32; i += 256) {
    int r = i >> 5, d = i & 31;
    qs[i] = __bfloat162float(z[((size_t)(l0 + r) * B_ + b) * PROJ_ + h * 32 + d]) * scale;
  }
  const int smax = l0 + 7;
  const int ntile = (smax + 128) / 128;

  for (int t = 0; t < ntile; t++) {
    int s0 = t * 128;
    __syncthreads();
    for (int i = tid; i < 128 * 32; i += 256) {
      int j = i >> 5, d = i & 31;
      int s = s0 + j;
      kvt[j * 33 + d] = (s <= smax)
          ? __bfloat162float(kv[((size_t)s * B_ + b) * 512 + h * 32 + d]) : 0.f;
    }
    __syncthreads();
    for (int i = tid; i < 8 * 128; i += 256) {
      int r = i >> 7, j = i & 127;
      int s = s0 + j;
      float a = -1e30f;
      if (s <= l0 + r) {
        a = 0.f;
#pragma unroll
        for (int d = 0; d < 32; d++) a += qs[r * 32 + d] * kvt[j * 33 + d];
      }
      S[r * 1024 + s] = a;
    }
  }
  __syncthreads();
  const int ns = ntile * 128;
  {
    int r = tid >> 5, c = tid & 31;
    float m = -1e30f;
    for (int s = c; s < ns; s += 32) m = fmaxf(m, S[r * 1024 + s]);
    red[r * 32 + c] = m;
  }
  __syncthreads();
  if (tid < 8) {
    float m = -1e30f;
    for (int c = 0; c < 32; c++) m = fmaxf(m, red[tid * 32 + c]);
    rowmax[tid] = m;
  }
  __syncthreads();
  {
    int r = tid >> 5, c = tid & 31;
    float m = rowmax[r], sm = 0.f;
    for (int s = c; s < ns; s += 32) {
      float e = __expf(S[r * 1024 + s] - m);
      S[r * 1024 + s] = e;
      sm += e;
    }
    red[r * 32 + c] = sm;
  }
  __syncthreads();
  if (tid < 8) {
    float sm = 0.f;
    for (int c = 0; c < 32; c++) sm += red[tid * 32 + c];
    rowsum[tid] = sm;
  }
  const int r0 = tid >> 5, d0 = tid & 31;
  float o = 0.f;
  for (int t = 0; t < ntile; t++) {
    int s0 = t * 128;
    __syncthreads();
    for (int i = tid; i < 128 * 32; i += 256) {
      int j = i >> 5, d = i & 31;
      int s = s0 + j;
      kvt[j * 33 + d] = (s <= smax)
          ? __bfloat162float(kv[((size_t)s * B_ + b) * 512 + 256 + h * 32 + d]) : 0.f;
    }
    __syncthreads();
#pragma unroll 4
    for (int j = 0; j < 128; j++)
      o += S[r0 * 1024 + s0 + j] * kvt[j * 33 + d0];
  }
  size_t oi = ((size_t)(l0 + r0) * B_ + b) * PROJ_ + h * 32 + d0;
  float res = __bfloat162float(z[oi]);
  ao[oi] = __float2bfloat16(o / rowsum[r0] * alpha + res);
}

// ------------- SRU: 64 blocks x 64 thr, 8-step register prefetch chunks -------
__global__ __launch_bounds__(64) void k_sru(const __hip_bfloat16* __restrict__ U,
                                            __hip_bfloat16* __restrict__ h,
                                            const float* __restrict__ hidden,
                                            const float* __restrict__ wc,
                                            const float* __restrict__ bias) {
  int tid = blockIdx.x * 64 + threadIdx.x;  // 0..4095
  int b = tid >> 10, d = tid & 1023;
  float vf = wc[d], vr = wc[D_ + d];
  float bfs = bias[d], brs = bias[D_ + d];
  float c = hidden[b * D_ + d];
  const __hip_bfloat16* up = U + (size_t)b * 3 * D_ + 3 * d;
  __hip_bfloat16* hp = h + (size_t)b * D_ + d;
  const int US = B_ * 3 * D_, HS = B_ * D_;
  for (int l0 = 0; l0 < L_; l0 += 8) {
    float u0[8], u1[8], u2[8], rs[8];
#pragma unroll
    for (int j = 0; j < 8; j++) {
      u0[j] = __bfloat162float(up[(size_t)j * US + 0]);
      u1[j] = __bfloat162float(up[(size_t)j * US + 1]);
      u2[j] = __bfloat162float(up[(size_t)j * US + 2]);
      rs[j] = __bfloat162float(hp[(size_t)j * HS]);
    }
#pragma unroll
    for (int j = 0; j < 8; j++) {
      float f = __builtin_amdgcn_rcpf(1.f + __expf(-(u1[j] + bfs + vf * c)));
      c = u0[j] + f * (c - u0[j]);
      float r = __builtin_amdgcn_rcpf(1.f + __expf(-(u2[j] + brs + vr * c)));
      hp[(size_t)j * HS] = __float2bfloat16(rs[j] + r * (c - rs[j]));
    }
    up += (size_t)8 * US;
    hp += (size_t)8 * HS;
  }
}

// ---------------- finalize: combine chunk partials -> fp32 loss ----------------
__global__ __launch_bounds__(256) void k_finalize(const float2* __restrict__ lse,
                                                  const float* __restrict__ logitY,
                                                  float* __restrict__ out) {
  int row = blockIdx.x * 256 + threadIdx.x;
  float M = -1e30f, S = 0.f;
  for (int c = 0; c < V_ / 64; c++) {
    float2 p = lse[(size_t)c * M_ + row];
    if (p.x > M) {
      S = S * __expf(M - p.x) + p.y;
      M = p.x;
    } else {
      S += p.y * __expf(p.x - M);
    }
  }
  out[row] = M + logf(S) - logitY[row];
}

extern "C" void kernel_launch(void* const* d_in, const int* in_sizes, int n_in,
                              void* d_out, int out_size, void* d_ws, size_t ws_size,
                              hipStream_t stream) {
  const int* x = (const int*)d_in[0];
  const int* y = (const int*)d_in[1];
  const float* hidden = (const float*)d_in[2];
  const float* emb = (const float*)d_in[3];
  const float* W1 = (const float*)d_in[4];
  const float* W2 = (const float*)d_in[5];
  const float* W3 = (const float*)d_in[6];
  const float* alpha = (const float*)d_in[7];
  const float* wc = (const float*)d_in[8];
  const float* bias = (const float*)d_in[9];
  const float* Wout = (const float*)d_in[10];
  const float* bout = (const float*)d_in[11];

  char* ws = (char*)d_ws;
  __hip_bfloat16* h16  = (__hip_bfloat16*)(ws + 0);          // 8 MB
  __hip_bfloat16* z16  = (__hip_bfloat16*)(ws + 8388608);    // 2 MB
  __hip_bfloat16* kv16 = (__hip_bfloat16*)(ws + 10485760);   // 4 MB
  __hip_bfloat16* ao16 = (__hip_bfloat16*)(ws + 14680064);   // 2 MB
  __hip_bfloat16* W1t  = (__hip_bfloat16*)(ws + 16777216);   // 2 MB  [4][256][1024]
  __hip_bfloat16* W2t  = (__hip_bfloat16*)(ws + 18874368);   // 1 MB  [4][512][256]
  __hip_bfloat16* W3t  = (__hip_bfloat16*)(ws + 19922944);   // 6 MB  [4][3072][256]
  __hip_bfloat16* U16  = (__hip_bfloat16*)(ws + 26214400);   // 24 MB
  const bool fast = ws_size >= 109723648ull;
  __hip_bfloat16* Woutt = (__hip_bfloat16*)(ws + 26214400);  // 64 MB [32000][1024]
  float2* lse    = (float2*)(ws + (fast ? 93323264u : 26214400u));  // 16 MB
  float* logitY  = (float*)(ws + (fast ? 109707264u : 42598400u));  // 16 KB
  float* out     = (float*)d_out;

  k_embed<<<4096, 256, 0, stream>>>(x, emb, h16);
  k_transpose<<<dim3(4, 16, 4), 256, 0, stream>>>(W1, W1t, D_, PROJ_,
                                                  (long)D_ * PROJ_, (long)PROJ_ * D_);
  k_transpose<<<dim3(8, 4, 4), 256, 0, stream>>>(W2, W2t, PROJ_, 2 * PROJ_,
                                                 (long)PROJ_ * 2 * PROJ_,
                                                 (long)2 * PROJ_ * PROJ_);
  k_transpose<<<dim3(48, 4, 4), 256, 0, stream>>>(W3, W3t, PROJ_, 3 * D_,
                                                  (long)PROJ_ * 3 * D_,
                                                  (long)3 * D_ * PROJ_);
  for (int i = 0; i < 4; i++) {
    k_gemm_bt<false><<<dim3(32, 2), 256, 0, stream>>>(
        h16, W1t + (size_t)i * PROJ_ * D_, z16, D_, PROJ_,
        nullptr, nullptr, nullptr, nullptr);
    k_gemm_bt<false><<<dim3(32, 4), 256, 0, stream>>>(
        z16, W2t + (size_t)i * 2 * PROJ_ * PROJ_, kv16, PROJ_, 2 * PROJ_,
        nullptr, nullptr, nullptr, nullptr);
    k_attn<<<dim3(L_ / 8, B_ * H_), 256, 0, stream>>>(z16, kv16, ao16, alpha + i);
    k_gemm_bt<false><<<dim3(32, 24), 256, 0, stream>>>(
        ao16, W3t + (size_t)i * 3 * D_ * PROJ_, U16, PROJ_, 3 * D_,
        nullptr, nullptr, nullptr, nullptr);
    k_sru<<<64, 64, 0, stream>>>(U16, h16, hidden + (size_t)i * B_ * D_,
                                 wc + (size_t)i * 2 * D_, bias + (size_t)i * 2 * D_);
  }
  if (fast) {
    k_transpose<<<dim3(500, 16, 1), 256, 0, stream>>>(Wout, Woutt, D_, V_, 0, 0);
    k_gemm_bt<true><<<dim3(32, V_ / 128), 256, 0, stream>>>(
        h16, Woutt, nullptr, D_, V_, bout, y, lse, logitY);
  } else {
    k_gemm_cls_f32<<<dim3(32, V_ / 128), 256, 0, stream>>>(
        h16, Wout, D_, V_, bout, y, lse, logitY);
  }
  k_finalize<<<16, 256, 0, stream>>>(lse, logitY, out);
}

// Round 5
// 1438.592 us; speedup vs baseline: 2.6613x; 1.8569x over previous
//
#include <hip/hip_runtime.h>
#include <hip/hip_bf16.h>
#include <stdint.h>

#define L_ 1024
#define B_ 4
#define D_ 1024
#define PROJ_ 256
#define H_ 8
#define V_ 32000
#define M_ 4096

typedef __bf16 bf16x8 __attribute__((ext_vector_type(8)));
typedef float f32x4 __attribute__((ext_vector_type(4)));

#define AS3(p) ((__attribute__((address_space(3))) void*)(p))
#define AS1(p) ((const __attribute__((address_space(1))) void*)(p))

// ---------------- embedding gather -> bf16 ----------------
__global__ __launch_bounds__(256) void k_embed(const int* __restrict__ x,
                                               const float* __restrict__ emb,
                                               __hip_bfloat16* __restrict__ h) {
  int gid = blockIdx.x * 256 + threadIdx.x;
  int row = gid >> 8;
  int d0 = (gid & 255) << 2;
  int tok = x[row];
  const float4 v = *(const float4*)(emb + (size_t)tok * D_ + d0);
  union { __hip_bfloat16 o[4]; uint2 u; } cv;
  cv.o[0] = __float2bfloat16(v.x);
  cv.o[1] = __float2bfloat16(v.y);
  cv.o[2] = __float2bfloat16(v.z);
  cv.o[3] = __float2bfloat16(v.w);
  *(uint2*)(h + (size_t)row * D_ + d0) = cv.u;
}

// ------------- transpose-convert: fp32 [K][N] -> bf16 [N][K], layer batched ---
__global__ __launch_bounds__(256) void k_transpose(const float* __restrict__ in,
                                                   __hip_bfloat16* __restrict__ out,
                                                   int K, int N,
                                                   long in_stride, long out_stride) {
  __shared__ float t[64][65];
  in += (size_t)blockIdx.z * in_stride;
  out += (size_t)blockIdx.z * out_stride;
  int n0 = blockIdx.x * 64, k0 = blockIdx.y * 64;
  int r = threadIdx.x >> 4, c4 = (threadIdx.x & 15) << 2;
#pragma unroll
  for (int p = 0; p < 4; p++) {
    float4 v = *(const float4*)(in + (size_t)(k0 + p * 16 + r) * N + n0 + c4);
    t[p * 16 + r][c4 + 0] = v.x;
    t[p * 16 + r][c4 + 1] = v.y;
    t[p * 16 + r][c4 + 2] = v.z;
    t[p * 16 + r][c4 + 3] = v.w;
  }
  __syncthreads();
  int n = threadIdx.x >> 2, kg = (threadIdx.x & 3) << 4;
  union { __hip_bfloat16 b[16]; uint4 u[2]; } cv;
#pragma unroll
  for (int i = 0; i < 16; i++) cv.b[i] = __float2bfloat16(t[kg + i][n]);
  uint4* op = (uint4*)(out + (size_t)(n0 + n) * K + k0 + kg);
  op[0] = cv.u[0];
  op[1] = cv.u[1];
}

// ------------- m97-style GEMM + XOR-swizzled LDS: A[M][K] bf16, Bt[N][K] bf16 ---
template <bool CLS>
__global__ __launch_bounds__(256) void k_gemm_bt(
    const __hip_bfloat16* __restrict__ A, const __hip_bfloat16* __restrict__ Bt,
    __hip_bfloat16* __restrict__ C, int K, int N,
    const float* __restrict__ bout, const int* __restrict__ y,
    float2* __restrict__ lse, float* __restrict__ logitY) {
  __shared__ __hip_bfloat16 As[128 * 64];
  __shared__ __hip_bfloat16 Bs[128 * 64];
  const int tid = threadIdx.x;
  const int lane = tid & 63, wave = tid >> 6;
  const int quad = lane >> 4, l16 = lane & 15;
  const int wm = wave & 1, wn = wave >> 1;
  const int row0 = blockIdx.x * 128, col0 = blockIdx.y * 128;

  f32x4 acc[4][4] = {};

  const __hip_bfloat16* Abase = A + (size_t)row0 * K;
  const __hip_bfloat16* Bbase = Bt + (size_t)col0 * K;
  const int m_s = tid >> 3;
  const int ko_sw = (((tid & 7) ^ (m_s & 7)) << 3);
  const int xr = l16 & 7;

  for (int k0 = 0; k0 < K; k0 += 64) {
    __syncthreads();
#pragma unroll
    for (int call = 0; call < 4; call++) {
      int m = m_s + call * 32;
      __builtin_amdgcn_global_load_lds(AS1(Abase + (size_t)m * K + k0 + ko_sw),
                                       AS3(As + (call * 256 + wave * 64) * 8),
                                       16, 0, 0);
      __builtin_amdgcn_global_load_lds(AS1(Bbase + (size_t)m * K + k0 + ko_sw),
                                       AS3(Bs + (call * 256 + wave * 64) * 8),
                                       16, 0, 0);
    }
    __syncthreads();
#pragma unroll
    for (int kk = 0; kk < 2; kk++) {
      bf16x8 af[4], bfr[4];
#pragma unroll
      for (int mi = 0; mi < 4; mi++)
        af[mi] = *(const bf16x8*)(As + (wm * 64 + mi * 16 + l16) * 64 +
                                  (((kk * 4 + quad) ^ xr) << 3));
#pragma unroll
      for (int ni = 0; ni < 4; ni++)
        bfr[ni] = *(const bf16x8*)(Bs + (wn * 64 + ni * 16 + l16) * 64 +
                                   (((kk * 4 + quad) ^ xr) << 3));
#pragma unroll
      for (int mi = 0; mi < 4; mi++)
#pragma unroll
        for (int ni = 0; ni < 4; ni++)
          acc[mi][ni] = __builtin_amdgcn_mfma_f32_16x16x32_bf16(af[mi], bfr[ni],
                                                                acc[mi][ni], 0, 0, 0);
    }
  }

  if constexpr (!CLS) {
#pragma unroll
    for (int mi = 0; mi < 4; mi++)
#pragma unroll
      for (int ni = 0; ni < 4; ni++)
#pragma unroll
        for (int r = 0; r < 4; r++) {
          int row = row0 + wm * 64 + mi * 16 + quad * 4 + r;
          int col = col0 + wn * 64 + ni * 16 + l16;
          C[(size_t)row * N + col] = __float2bfloat16(acc[mi][ni][r]);
        }
  } else {
    const int chunk = blockIdx.y * 2 + wn;
    float bv[4];
#pragma unroll
    for (int ni = 0; ni < 4; ni++)
      bv[ni] = bout[col0 + wn * 64 + ni * 16 + l16];
#pragma unroll
    for (int mi = 0; mi < 4; mi++) {
#pragma unroll
      for (int r = 0; r < 4; r++) {
        int row = row0 + wm * 64 + mi * 16 + quad * 4 + r;
        float v0 = acc[mi][0][r] + bv[0];
        float v1 = acc[mi][1][r] + bv[1];
        float v2 = acc[mi][2][r] + bv[2];
        float v3 = acc[mi][3][r] + bv[3];
        int yv = y[row];
        int cb = col0 + wn * 64 + l16;
        if (yv == cb + 0)  logitY[row] = v0;
        if (yv == cb + 16) logitY[row] = v1;
        if (yv == cb + 32) logitY[row] = v2;
        if (yv == cb + 48) logitY[row] = v3;
        float m = fmaxf(fmaxf(v0, v1), fmaxf(v2, v3));
#pragma unroll
        for (int off = 1; off < 16; off <<= 1)
          m = fmaxf(m, __shfl_xor(m, off, 64));
        float s = __expf(v0 - m) + __expf(v1 - m) + __expf(v2 - m) + __expf(v3 - m);
#pragma unroll
        for (int off = 1; off < 16; off <<= 1)
          s += __shfl_xor(s, off, 64);
        if (l16 == 0)
          lse[(size_t)chunk * M_ + row] = make_float2(m, s);
      }
    }
  }
}

// ------------- fallback classifier: fp32 B staged through LDS (validated) ---
__global__ __launch_bounds__(256) void k_gemm_cls_f32(
    const __hip_bfloat16* __restrict__ A, const float* __restrict__ B,
    int K, int N, const float* __restrict__ bout, const int* __restrict__ y,
    float2* __restrict__ lse, float* __restrict__ logitY) {
  __shared__ __hip_bfloat16 As[128 * 40];
  __shared__ __hip_bfloat16 Bs[128 * 40];
  const int tid = threadIdx.x;
  const int lane = tid & 63, wave = tid >> 6;
  const int quad = lane >> 4, l16 = lane & 15;
  const int wm = wave & 1, wn = wave >> 1;
  const int row0 = blockIdx.x * 128, col0 = blockIdx.y * 128;
  f32x4 acc[4][4] = {};
  const int a_m = tid >> 1, a_k = (tid & 1) << 4;
  const int b_k = tid >> 3, b_n = (tid & 7) << 4;
  for (int k0 = 0; k0 < K; k0 += 32) {
    const uint4* ap = (const uint4*)(A + (size_t)(row0 + a_m) * K + k0 + a_k);
    uint4 av0 = ap[0];
    uint4 av1 = ap[1];
    const float* bp = B + (size_t)(k0 + b_k) * N + col0 + b_n;
    float4 bv0 = *(const float4*)(bp + 0);
    float4 bv1 = *(const float4*)(bp + 4);
    float4 bv2 = *(const float4*)(bp + 8);
    float4 bv3 = *(const float4*)(bp + 12);
    __syncthreads();
    *(uint4*)(As + a_m * 40 + a_k) = av0;
    *(uint4*)(As + a_m * 40 + a_k + 8) = av1;
    {
      float tmp[16] = {bv0.x, bv0.y, bv0.z, bv0.w, bv1.x, bv1.y, bv1.z, bv1.w,
                       bv2.x, bv2.y, bv2.z, bv2.w, bv3.x, bv3.y, bv3.z, bv3.w};
#pragma unroll
      for (int j = 0; j < 16; j++)
        Bs[(b_n + j) * 40 + b_k] = __float2bfloat16(tmp[j]);
    }
    __syncthreads();
    bf16x8 af[4], bfr[4];
#pragma unroll
    for (int mi = 0; mi < 4; mi++)
      af[mi] = *(const bf16x8*)(As + (wm * 64 + mi * 16 + l16) * 40 + quad * 8);
#pragma unroll
    for (int ni = 0; ni < 4; ni++)
      bfr[ni] = *(const bf16x8*)(Bs + (wn * 64 + ni * 16 + l16) * 40 + quad * 8);
#pragma unroll
    for (int mi = 0; mi < 4; mi++)
#pragma unroll
      for (int ni = 0; ni < 4; ni++)
        acc[mi][ni] = __builtin_amdgcn_mfma_f32_16x16x32_bf16(af[mi], bfr[ni],
                                                              acc[mi][ni], 0, 0, 0);
  }
  const int chunk = blockIdx.y * 2 + wn;
  float bv[4];
#pragma unroll
  for (int ni = 0; ni < 4; ni++)
    bv[ni] = bout[col0 + wn * 64 + ni * 16 + l16];
#pragma unroll
  for (int mi = 0; mi < 4; mi++) {
#pragma unroll
    for (int r = 0; r < 4; r++) {
      int row = row0 + wm * 64 + mi * 16 + quad * 4 + r;
      float v0 = acc[mi][0][r] + bv[0];
      float v1 = acc[mi][1][r] + bv[1];
      float v2 = acc[mi][2][r] + bv[2];
      float v3 = acc[mi][3][r] + bv[3];
      int yv = y[row];
      int cb = col0 + wn * 64 + l16;
      if (yv == cb + 0)  logitY[row] = v0;
      if (yv == cb + 16) logitY[row] = v1;
      if (yv == cb + 32) logitY[row] = v2;
      if (yv == cb + 48) logitY[row] = v3;
      float m = fmaxf(fmaxf(v0, v1), fmaxf(v2, v3));
#pragma unroll
      for (int off = 1; off < 16; off <<= 1)
        m = fmaxf(m, __shfl_xor(m, off, 64));
      float s = __expf(v0 - m) + __expf(v1 - m) + __expf(v2 - m) + __expf(v3 - m);
#pragma unroll
      for (int off = 1; off < 16; off <<= 1)
        s += __shfl_xor(s, off, 64);
      if (l16 == 0)
        lse[(size_t)chunk * M_ + row] = make_float2(m, s);
    }
  }
}

// ---------------- flash-style MFMA attention ----------------
// Grid (16, 32): blockIdx.x = 64-row Q tile, blockIdx.y = (b,h).
// 4 waves; wave w owns Q rows [q0+16w, q0+16w+16). KV tiles of 128.
// QK^T: mfma_16x16x32 (A = Q [m][d], B = K [s][d]); online softmax in regs
// (C-layout row = quad*4+reg); P -> bf16 -> LDS (wave-private rows, no barrier
// needed); PV: A = P [m][s], B = V^T [d][s] staged transposed in LDS.
// Strides: Qs/Ks 40 (80 B, 16B-aligned), Ps/Vt 136 (272 B, 16B-aligned).
__global__ __launch_bounds__(256) void k_attn_mfma(
    const __hip_bfloat16* __restrict__ z, const __hip_bfloat16* __restrict__ kv,
    __hip_bfloat16* __restrict__ ao, const float* __restrict__ alpha_p) {
  __shared__ __hip_bfloat16 Qs[64 * 40];
  __shared__ __hip_bfloat16 Ks[128 * 40];
  __shared__ __hip_bfloat16 Vt[32 * 136];
  __shared__ __hip_bfloat16 Ps[64 * 136];
  const int tid = threadIdx.x;
  const int lane = tid & 63, wave = tid >> 6;
  const int quad = lane >> 4, l16 = lane & 15;
  const int bh = blockIdx.y, b = bh >> 3, h = bh & 7;
  const int q0 = blockIdx.x * 64;
  const float scale = 0.17677669529663687f;  // 32^-0.5

  // stage Q: 64 rows x 32 d; thread: row = tid>>2, chunk = tid&3 (8 bf16)
  {
    int r = tid >> 2, c = (tid & 3) << 3;
    *(uint4*)(Qs + r * 40 + c) =
        *(const uint4*)(z + ((size_t)(q0 + r) * B_ + b) * PROJ_ + h * 32 + c);
  }

  float m_i[4] = {-1e30f, -1e30f, -1e30f, -1e30f};
  float l_i[4] = {0.f, 0.f, 0.f, 0.f};
  f32x4 o_acc[2] = {};

  const int ntile = (q0 + 191) >> 7;  // ceil((q0+64)/128); s0 <= q0 always

  for (int t = 0; t < ntile; t++) {
    const int s0 = t << 7;
    __syncthreads();  // prior-iter Ks/Vt readers done; publishes Qs on t=0
    {  // stage K: row = tid>>1, half = tid&1 (16 bf16 = 2 uint4)
      int r = tid >> 1, c = (tid & 1) << 4;
      const uint4* kp =
          (const uint4*)(kv + ((size_t)(s0 + r) * B_ + b) * 512 + h * 32 + c);
      *(uint4*)(Ks + r * 40 + c) = kp[0];
      *(uint4*)(Ks + r * 40 + c + 8) = kp[1];
    }
    {  // stage V transposed: row s = tid>>1, dbase = (tid&1)*16
      int s = tid >> 1, dbase = (tid & 1) << 4;
      const __hip_bfloat16* vp =
          kv + ((size_t)(s0 + s) * B_ + b) * 512 + 256 + h * 32 + dbase;
      union { uint4 u; __hip_bfloat16 e[8]; } t0, t1;
      t0.u = *(const uint4*)vp;
      t1.u = *(const uint4*)(vp + 8);
#pragma unroll
      for (int j = 0; j < 8; j++) {
        Vt[(dbase + j) * 136 + s] = t0.e[j];
        Vt[(dbase + 8 + j) * 136 + s] = t1.e[j];
      }
    }
    __syncthreads();

    // QK^T: wave's 16 rows x 128 cols
    f32x4 sacc[8] = {};
    {
      bf16x8 aq = *(const bf16x8*)(Qs + (wave * 16 + l16) * 40 + quad * 8);
#pragma unroll
      for (int ni = 0; ni < 8; ni++) {
        bf16x8 bk = *(const bf16x8*)(Ks + (ni * 16 + l16) * 40 + quad * 8);
        sacc[ni] = __builtin_amdgcn_mfma_f32_16x16x32_bf16(aq, bk, sacc[ni], 0, 0, 0);
      }
    }

    // online softmax (per reg-row r: global row = q0 + wave*16 + quad*4 + r)
#pragma unroll
    for (int r = 0; r < 4; r++) {
      const int qrow = q0 + wave * 16 + quad * 4 + r;
      float mx = -1e30f;
#pragma unroll
      for (int ni = 0; ni < 8; ni++) {
        int s = s0 + ni * 16 + l16;
        float v = (s <= qrow) ? sacc[ni][r] * scale : -1e30f;
        sacc[ni][r] = v;
        mx = fmaxf(mx, v);
      }
#pragma unroll
      for (int off = 1; off < 16; off <<= 1)
        mx = fmaxf(mx, __shfl_xor(mx, off, 64));
      float mnew = fmaxf(m_i[r], mx);
      float al = __expf(m_i[r] - mnew);
      m_i[r] = mnew;
      float ps = 0.f;
#pragma unroll
      for (int ni = 0; ni < 8; ni++) {
        float p = __expf(sacc[ni][r] - mnew);
        Ps[(wave * 16 + quad * 4 + r) * 136 + ni * 16 + l16] = __float2bfloat16(p);
        ps += p;
      }
#pragma unroll
      for (int off = 1; off < 16; off <<= 1)
        ps += __shfl_xor(ps, off, 64);
      l_i[r] = l_i[r] * al + ps;
      o_acc[0][r] *= al;
      o_acc[1][r] *= al;
    }

    // PV: O[16 x 32] += P[16 x 128] @ V[128 x 32]  (wave-private Ps rows)
#pragma unroll
    for (int ks = 0; ks < 4; ks++) {
      bf16x8 ap = *(const bf16x8*)(Ps + (wave * 16 + l16) * 136 + ks * 32 + quad * 8);
#pragma unroll
      for (int ni = 0; ni < 2; ni++) {
        bf16x8 bv = *(const bf16x8*)(Vt + (ni * 16 + l16) * 136 + ks * 32 + quad * 8);
        o_acc[ni] = __builtin_amdgcn_mfma_f32_16x16x32_bf16(ap, bv, o_acc[ni], 0, 0, 0);
      }
    }
  }

  // epilogue: ao = O/l * alpha + z
  const float arz = alpha_p[0];
#pragma unroll
  for (int ni = 0; ni < 2; ni++)
#pragma unroll
    for (int r = 0; r < 4; r++) {
      int row = q0 + wave * 16 + quad * 4 + r;
      size_t oi = ((size_t)row * B_ + b) * PROJ_ + h * 32 + ni * 16 + l16;
      float res = __bfloat162float(z[oi]);
      ao[oi] = __float2bfloat16(o_acc[ni][r] / l_i[r] * arz + res);
    }
}

// ------------- SRU: 64 blocks x 64 thr, 8-step register prefetch chunks -------
__global__ __launch_bounds__(64) void k_sru(const __hip_bfloat16* __restrict__ U,
                                            __hip_bfloat16* __restrict__ h,
                                            const float* __restrict__ hidden,
                                            const float* __restrict__ wc,
                                            const float* __restrict__ bias) {
  int tid = blockIdx.x * 64 + threadIdx.x;  // 0..4095
  int b = tid >> 10, d = tid & 1023;
  float vf = wc[d], vr = wc[D_ + d];
  float bfs = bias[d], brs = bias[D_ + d];
  float c = hidden[b * D_ + d];
  const __hip_bfloat16* up = U + (size_t)b * 3 * D_ + 3 * d;
  __hip_bfloat16* hp = h + (size_t)b * D_ + d;
  const int US = B_ * 3 * D_, HS = B_ * D_;
  for (int l0 = 0; l0 < L_; l0 += 8) {
    float u0[8], u1[8], u2[8], rs[8];
#pragma unroll
    for (int j = 0; j < 8; j++) {
      u0[j] = __bfloat162float(up[(size_t)j * US + 0]);
      u1[j] = __bfloat162float(up[(size_t)j * US + 1]);
      u2[j] = __bfloat162float(up[(size_t)j * US + 2]);
      rs[j] = __bfloat162float(hp[(size_t)j * HS]);
    }
#pragma unroll
    for (int j = 0; j < 8; j++) {
      float f = __builtin_amdgcn_rcpf(1.f + __expf(-(u1[j] + bfs + vf * c)));
      c = u0[j] + f * (c - u0[j]);
      float r = __builtin_amdgcn_rcpf(1.f + __expf(-(u2[j] + brs + vr * c)));
      hp[(size_t)j * HS] = __float2bfloat16(rs[j] + r * (c - rs[j]));
    }
    up += (size_t)8 * US;
    hp += (size_t)8 * HS;
  }
}

// ---------------- finalize: combine chunk partials -> fp32 loss ----------------
__global__ __launch_bounds__(256) void k_finalize(const float2* __restrict__ lse,
                                                  const float* __restrict__ logitY,
                                                  float* __restrict__ out) {
  int row = blockIdx.x * 256 + threadIdx.x;
  float M = -1e30f, S = 0.f;
  for (int c = 0; c < V_ / 64; c++) {
    float2 p = lse[(size_t)c * M_ + row];
    if (p.x > M) {
      S = S * __expf(M - p.x) + p.y;
      M = p.x;
    } else {
      S += p.y * __expf(p.x - M);
    }
  }
  out[row] = M + logf(S) - logitY[row];
}

extern "C" void kernel_launch(void* const* d_in, const int* in_sizes, int n_in,
                              void* d_out, int out_size, void* d_ws, size_t ws_size,
                              hipStream_t stream) {
  const int* x = (const int*)d_in[0];
  const int* y = (const int*)d_in[1];
  const float* hidden = (const float*)d_in[2];
  const float* emb = (const float*)d_in[3];
  const float* W1 = (const float*)d_in[4];
  const float* W2 = (const float*)d_in[5];
  const float* W3 = (const float*)d_in[6];
  const float* alpha = (const float*)d_in[7];
  const float* wc = (const float*)d_in[8];
  const float* bias = (const float*)d_in[9];
  const float* Wout = (const float*)d_in[10];
  const float* bout = (const float*)d_in[11];

  char* ws = (char*)d_ws;
  __hip_bfloat16* h16  = (__hip_bfloat16*)(ws + 0);          // 8 MB
  __hip_bfloat16* z16  = (__hip_bfloat16*)(ws + 8388608);    // 2 MB
  __hip_bfloat16* kv16 = (__hip_bfloat16*)(ws + 10485760);   // 4 MB
  __hip_bfloat16* ao16 = (__hip_bfloat16*)(ws + 14680064);   // 2 MB
  __hip_bfloat16* W1t  = (__hip_bfloat16*)(ws + 16777216);   // 2 MB  [4][256][1024]
  __hip_bfloat16* W2t  = (__hip_bfloat16*)(ws + 18874368);   // 1 MB  [4][512][256]
  __hip_bfloat16* W3t  = (__hip_bfloat16*)(ws + 19922944);   // 6 MB  [4][3072][256]
  __hip_bfloat16* U16  = (__hip_bfloat16*)(ws + 26214400);   // 24 MB
  const bool fast = ws_size >= 109723648ull;
  __hip_bfloat16* Woutt = (__hip_bfloat16*)(ws + 26214400);  // 64 MB [32000][1024]
  float2* lse    = (float2*)(ws + (fast ? 93323264u : 26214400u));  // 16 MB
  float* logitY  = (float*)(ws + (fast ? 109707264u : 42598400u));  // 16 KB
  float* out     = (float*)d_out;

  k_embed<<<4096, 256, 0, stream>>>(x, emb, h16);
  k_transpose<<<dim3(4, 16, 4), 256, 0, stream>>>(W1, W1t, D_, PROJ_,
                                                  (long)D_ * PROJ_, (long)PROJ_ * D_);
  k_transpose<<<dim3(8, 4, 4), 256, 0, stream>>>(W2, W2t, PROJ_, 2 * PROJ_,
                                                 (long)PROJ_ * 2 * PROJ_,
                                                 (long)2 * PROJ_ * PROJ_);
  k_transpose<<<dim3(48, 4, 4), 256, 0, stream>>>(W3, W3t, PROJ_, 3 * D_,
                                                  (long)PROJ_ * 3 * D_,
                                                  (long)3 * D_ * PROJ_);
  for (int i = 0; i < 4; i++) {
    k_gemm_bt<false><<<dim3(32, 2), 256, 0, stream>>>(
        h16, W1t + (size_t)i * PROJ_ * D_, z16, D_, PROJ_,
        nullptr, nullptr, nullptr, nullptr);
    k_gemm_bt<false><<<dim3(32, 4), 256, 0, stream>>>(
        z16, W2t + (size_t)i * 2 * PROJ_ * PROJ_, kv16, PROJ_, 2 * PROJ_,
        nullptr, nullptr, nullptr, nullptr);
    k_attn_mfma<<<dim3(16, 32), 256, 0, stream>>>(z16, kv16, ao16, alpha + i);
    k_gemm_bt<false><<<dim3(32, 24), 256, 0, stream>>>(
        ao16, W3t + (size_t)i * 3 * D_ * PROJ_, U16, PROJ_, 3 * D_,
        nullptr, nullptr, nullptr, nullptr);
    k_sru<<<64, 64, 0, stream>>>(U16, h16, hidden + (size_t)i * B_ * D_,
                                 wc + (size_t)i * 2 * D_, bias + (size_t)i * 2 * D_);
  }
  if (fast) {
    k_transpose<<<dim3(500, 16, 1), 256, 0, stream>>>(Wout, Woutt, D_, V_, 0, 0);
    k_gemm_bt<true><<<dim3(32, V_ / 128), 256, 0, stream>>>(
        h16, Woutt, nullptr, D_, V_, bout, y, lse, logitY);
  } else {
    k_gemm_cls_f32<<<dim3(32, V_ / 128), 256, 0, stream>>>(
        h16, Wout, D_, V_, bout, y, lse, logitY);
  }
  k_finalize<<<16, 256, 0, stream>>>(lse, logitY, out);
}